// Round 1
// baseline (1795.492 us; speedup 1.0000x reference)
//
#include <hip/hip_runtime.h>

#define Hdim 512
#define Ddim 64
#define Bdim 512
#define NSTEPS 8

// ---------------------------------------------------------------------------
// Gt[k*512 + j] = W2[j,k] * sum_m W1[m,j] * W3[k,m]   (input-independent)
// trace_b = sum_{j,k} u[b,j] * G[j,k] * v[b,k],  u=1-h1^2, v=1-h2^2
// ---------------------------------------------------------------------------
__global__ __launch_bounds__(256) void g_precompute_kernel(
    const float* __restrict__ W1, const float* __restrict__ W2,
    const float* __restrict__ W3, float* __restrict__ Gt) {
  int gid = blockIdx.x * 256 + threadIdx.x;  // 512*512 threads
  int k = gid >> 9;
  int j = gid & 511;
  float s = 0.f;
#pragma unroll
  for (int m = 0; m < Ddim; ++m)
    s = fmaf(W1[m * Hdim + j], W3[k * Ddim + m], s);
  Gt[gid] = s * W2[j * Hdim + k];
}

__global__ __launch_bounds__(256) void init_kernel(
    const float* __restrict__ x, float* __restrict__ xb,
    float* __restrict__ tr, float* __restrict__ ld) {
  int gid = blockIdx.x * 256 + threadIdx.x;
  if (gid < Bdim * Ddim) xb[gid] = x[gid];
  if (gid < 4 * Bdim) tr[gid] = 0.f;
  if (gid < Bdim) ld[gid] = 0.f;
}

// h1 = tanh( [xb + c*kprev, t] @ W1 + b1 )     (B x H)
__global__ __launch_bounds__(256) void l1_kernel(
    const float* __restrict__ xb, const float* __restrict__ kprev, float c,
    float t, const float* __restrict__ W1, const float* __restrict__ b1,
    float* __restrict__ h1) {
  int gid = blockIdx.x * 256 + threadIdx.x;  // b*512 + j
  int b = gid >> 9;
  int j = gid & 511;
  float acc = b1[j] + t * W1[Ddim * Hdim + j];  // t is input element 64
  const float* xr = xb + b * Ddim;
  const float* kr = kprev + b * Ddim;
#pragma unroll 8
  for (int i = 0; i < Ddim; ++i)
    acc = fmaf(fmaf(c, kr[i], xr[i]), W1[i * Hdim + j], acc);
  h1[gid] = tanhf(acc);
}

// h2 = tanh( h1 @ W2 + b2 )    (B x H), tiled 32b x 32k, h1 rows in LDS
__global__ __launch_bounds__(256) void l2_kernel(
    const float* __restrict__ h1, const float* __restrict__ W2,
    const float* __restrict__ b2, float* __restrict__ h2) {
  __shared__ float lds[32 * 512];
  int b0 = (blockIdx.x >> 4) * 32;
  int k0 = (blockIdx.x & 15) * 32;
  for (int i = threadIdx.x; i < 32 * 512; i += 256) lds[i] = h1[b0 * 512 + i];
  __syncthreads();
  int kl = threadIdx.x & 31;
  int bg = threadIdx.x >> 5;  // 8 groups of 4 rows
  int k = k0 + kl;
  const float* lr = lds + bg * 4 * 512;
  float a0 = 0.f, a1 = 0.f, a2 = 0.f, a3 = 0.f;
#pragma unroll 4
  for (int j = 0; j < 512; ++j) {
    float w = W2[j * 512 + k];
    a0 = fmaf(lr[j], w, a0);
    a1 = fmaf(lr[512 + j], w, a1);
    a2 = fmaf(lr[1024 + j], w, a2);
    a3 = fmaf(lr[1536 + j], w, a3);
  }
  float bb = b2[k];
  int ob = (b0 + bg * 4) * 512 + k;
  h2[ob] = tanhf(a0 + bb);
  h2[ob + 512] = tanhf(a1 + bb);
  h2[ob + 1024] = tanhf(a2 + bb);
  h2[ob + 1536] = tanhf(a3 + bb);
}

// blocks 0..255 : trace partials -> atomicAdd(-trace) into trs[b]
// blocks 256..383 : kx = h2 @ W3 + b3   (B x D)
__global__ __launch_bounds__(256) void l3_kernel(
    const float* __restrict__ h1, const float* __restrict__ h2,
    const float* __restrict__ W3, const float* __restrict__ b3,
    const float* __restrict__ Gt, float* __restrict__ kx,
    float* __restrict__ trs) {
  __shared__ float lds[32 * 512];
  if (blockIdx.x < 256) {
    int b0 = (blockIdx.x >> 4) * 32;
    int j0 = (blockIdx.x & 15) * 32;
    for (int i = threadIdx.x; i < 32 * 512; i += 256) {
      float v = h2[b0 * 512 + i];
      lds[i] = 1.f - v * v;  // v = 1 - h2^2
    }
    __syncthreads();
    int jl = threadIdx.x & 31;
    int bg = threadIdx.x >> 5;
    int j = j0 + jl;
    const float* lr = lds + bg * 4 * 512;
    float a0 = 0.f, a1 = 0.f, a2 = 0.f, a3 = 0.f;
#pragma unroll 4
    for (int k = 0; k < 512; ++k) {
      float g = Gt[k * 512 + j];
      a0 = fmaf(lr[k], g, a0);
      a1 = fmaf(lr[512 + k], g, a1);
      a2 = fmaf(lr[1024 + k], g, a2);
      a3 = fmaf(lr[1536 + k], g, a3);
    }
    int b = b0 + bg * 4;
    float t0 = h1[(b + 0) * 512 + j];
    float t1 = h1[(b + 1) * 512 + j];
    float t2 = h1[(b + 2) * 512 + j];
    float t3 = h1[(b + 3) * 512 + j];
    float p0 = a0 * (1.f - t0 * t0);
    float p1 = a1 * (1.f - t1 * t1);
    float p2 = a2 * (1.f - t2 * t2);
    float p3 = a3 * (1.f - t3 * t3);
#pragma unroll
    for (int off = 16; off; off >>= 1) {
      p0 += __shfl_down(p0, off, 32);
      p1 += __shfl_down(p1, off, 32);
      p2 += __shfl_down(p2, off, 32);
      p3 += __shfl_down(p3, off, 32);
    }
    if (jl == 0) {
      atomicAdd(trs + b + 0, -p0);
      atomicAdd(trs + b + 1, -p1);
      atomicAdd(trs + b + 2, -p2);
      atomicAdd(trs + b + 3, -p3);
    }
  } else {
    int bi = blockIdx.x - 256;
    int b = bi * 4 + (threadIdx.x >> 6);
    int m = threadIdx.x & 63;
    const float* h2r = h2 + b * 512;
    float acc = b3[m];
#pragma unroll 4
    for (int kk = 0; kk < 512; ++kk) acc = fmaf(h2r[kk], W3[kk * 64 + m], acc);
    kx[b * Ddim + m] = acc;
  }
}

// xb += dt/6 (k1+2k2+2k3+k4); ld += dt/6 (sum of -trace slots); re-zero tr.
__global__ __launch_bounds__(256) void combine_kernel(
    float* __restrict__ xb, const float* __restrict__ k1,
    const float* __restrict__ k2, const float* __restrict__ k3,
    const float* __restrict__ k4, float* __restrict__ ld,
    float* __restrict__ tr, float* __restrict__ out, int last) {
  int gid = blockIdx.x * 256 + threadIdx.x;
  const float dt = 1.f / NSTEPS;
  if (gid < Bdim * Ddim) {
    float v = xb[gid] +
              (dt / 6.f) * (k1[gid] + 2.f * k2[gid] + 2.f * k3[gid] + k4[gid]);
    xb[gid] = v;
    if (last) out[gid] = v;
  } else if (gid < Bdim * Ddim + Bdim) {
    int b = gid - Bdim * Ddim;
    float v = ld[b] + (dt / 6.f) * (tr[b] + 2.f * tr[512 + b] +
                                    2.f * tr[1024 + b] + tr[1536 + b]);
    ld[b] = v;
    tr[b] = 0.f;
    tr[512 + b] = 0.f;
    tr[1024 + b] = 0.f;
    tr[1536 + b] = 0.f;
    if (last) out[Bdim * Ddim + b] = v;
  }
}

extern "C" void kernel_launch(void* const* d_in, const int* in_sizes, int n_in,
                              void* d_out, int out_size, void* d_ws,
                              size_t ws_size, hipStream_t stream) {
  const float* x = (const float*)d_in[0];
  const float* W1 = (const float*)d_in[1];
  const float* b1 = (const float*)d_in[2];
  const float* W2 = (const float*)d_in[3];
  const float* b2 = (const float*)d_in[4];
  const float* W3 = (const float*)d_in[5];
  const float* b3 = (const float*)d_in[6];
  float* out = (float*)d_out;
  float* ws = (float*)d_ws;

  float* Gt = ws;               // 262144
  float* h1 = ws + 262144;      // 262144
  float* h2 = ws + 524288;      // 262144
  float* xb = ws + 786432;      // 32768
  float* kx0 = ws + 819200;     // 32768 x4
  float* kx1 = ws + 851968;
  float* kx2 = ws + 884736;
  float* kx3 = ws + 917504;
  float* tr = ws + 950272;      // 4*512
  float* ld = ws + 952320;      // 512
  float* kxs[4] = {kx0, kx1, kx2, kx3};

  g_precompute_kernel<<<1024, 256, 0, stream>>>(W1, W2, W3, Gt);
  init_kernel<<<128, 256, 0, stream>>>(x, xb, tr, ld);

  const float dt = 1.f / NSTEPS;
  for (int s = 0; s < NSTEPS; ++s) {
    float t0 = s * dt;
    const float cs[4] = {0.f, 0.5f * dt, 0.5f * dt, dt};
    const float ts[4] = {t0, t0 + 0.5f * dt, t0 + 0.5f * dt, t0 + dt};
    for (int g = 0; g < 4; ++g) {
      const float* kprev = (g == 0) ? xb : kxs[g - 1];
      l1_kernel<<<1024, 256, 0, stream>>>(xb, kprev, cs[g], ts[g], W1, b1, h1);
      l2_kernel<<<256, 256, 0, stream>>>(h1, W2, b2, h2);
      l3_kernel<<<384, 256, 0, stream>>>(h1, h2, W3, b3, Gt, kxs[g],
                                         tr + g * 512);
    }
    combine_kernel<<<130, 256, 0, stream>>>(xb, kx0, kx1, kx2, kx3, ld, tr,
                                            out, s == NSTEPS - 1);
  }
}